// Round 1
// baseline (275.484 us; speedup 1.0000x reference)
//
#include <hip/hip_runtime.h>

// Problem constants: B=16, DIM(C)=512, N=4096, H=8, HD=64, QKV rows = 8*129 = 1032.
#define NB 16
#define NC 512
#define NN 4096
#define NH 8

typedef __attribute__((ext_vector_type(8))) __bf16 bf16x8;
typedef __attribute__((ext_vector_type(4))) float f32x4;

__device__ __forceinline__ unsigned short f2bf(float f) {
    union { float f; unsigned u; } x; x.f = f;
    unsigned r = x.u + 0x7FFF + ((x.u >> 16) & 1);   // round-to-nearest-even
    return (unsigned short)(r >> 16);
}
__device__ __forceinline__ float bf2f(unsigned short u) {
    union { unsigned u; float f; } x; x.u = ((unsigned)u) << 16; return x.f;
}

// K0: repack Wv rows (head-interleaved) + Wp to bf16, gather bv.
__global__ void pack_kernel(const float* __restrict__ Wqkv, const float* __restrict__ bqkv,
                            const float* __restrict__ Wp,
                            unsigned short* __restrict__ Wv_bf, unsigned short* __restrict__ Wp_bf,
                            float* __restrict__ bv) {
    int t = blockIdx.x * 256 + threadIdx.x;          // 0 .. 512*512-1
    int j = t >> 9, c = t & 511;
    int h = j >> 6, d = j & 63;
    Wv_bf[t] = f2bf(Wqkv[((size_t)h * 129 + 65 + d) * 512 + c]);
    Wp_bf[t] = f2bf(Wp[t]);
    if (t < 512) bv[t] = bqkv[(t >> 6) * 129 + 65 + (t & 63)];
}

// K1: q[b,h,n] = Wq[h,:].x[b,:,n] + bq[h]   (fp32; weights are thread-uniform -> s_loads)
__global__ void q_kernel(const float* __restrict__ x, const float* __restrict__ Wqkv,
                         const float* __restrict__ bqkv, float* __restrict__ q) {
    int b = blockIdx.y, n0 = blockIdx.x * 256;
    int t = threadIdx.x;
    float acc[8] = {};
    const float* xp = x + (size_t)b * NC * NN + n0 + t;
#pragma unroll 4
    for (int c = 0; c < 512; c++) {
        float xv = xp[(size_t)c * NN];
#pragma unroll
        for (int h = 0; h < 8; h++) acc[h] += Wqkv[(size_t)h * 129 * 512 + c] * xv;
    }
#pragma unroll
    for (int h = 0; h < 8; h++)
        q[((size_t)b * 8 + h) * NN + n0 + t] = acc[h] + bqkv[h * 129];
}

// K2: softmax over N per (b,h); writes TRANSPOSED scores sT[b][n][h] (fp32).
__global__ void softmax_kernel(const float* __restrict__ q, float* __restrict__ sT) {
    int bh = blockIdx.x;                 // b*8+h
    int b = bh >> 3, h = bh & 7;
    int t = threadIdx.x;                 // 256
    __shared__ float red[8];
    const float* qp = q + (size_t)bh * NN;
    float v[16];
    float mx = -1e30f;
#pragma unroll
    for (int i = 0; i < 16; i++) { v[i] = qp[t + i * 256]; mx = fmaxf(mx, v[i]); }
#pragma unroll
    for (int o = 32; o; o >>= 1) mx = fmaxf(mx, __shfl_xor(mx, o));
    if ((t & 63) == 0) red[t >> 6] = mx;
    __syncthreads();
    mx = fmaxf(fmaxf(red[0], red[1]), fmaxf(red[2], red[3]));
    float s = 0.f;
#pragma unroll
    for (int i = 0; i < 16; i++) { v[i] = __expf(v[i] - mx); s += v[i]; }
#pragma unroll
    for (int o = 32; o; o >>= 1) s += __shfl_xor(s, o);
    __syncthreads();
    if ((t & 63) == 0) red[4 + (t >> 6)] = s;
    __syncthreads();
    float inv = 1.f / (red[4] + red[5] + red[6] + red[7]);
#pragma unroll
    for (int i = 0; i < 16; i++) {
        int n = t + i * 256;
        sT[((size_t)b * NN + n) * 8 + h] = v[i] * inv;
    }
}

// K1b: x [b][c][n] fp32  ->  xT [b][n][c] bf16  (LDS 64x64 tile transpose)
__global__ void transpose_kernel(const float* __restrict__ x, unsigned short* __restrict__ xT) {
    __shared__ unsigned short tile[64][66];          // pad to break bank conflicts
    int b = blockIdx.z, c0 = blockIdx.y * 64, n0 = blockIdx.x * 64;
    int t = threadIdx.x;                             // 256
    int r = t >> 4, cc = (t & 15) * 4;
    const float* xp = x + ((size_t)b * NC + c0) * NN + n0;
#pragma unroll
    for (int p = 0; p < 4; p++) {
        int row = r + p * 16;
        float4 v = *(const float4*)(xp + (size_t)row * NN + cc);
        tile[row][cc + 0] = f2bf(v.x);
        tile[row][cc + 1] = f2bf(v.y);
        tile[row][cc + 2] = f2bf(v.z);
        tile[row][cc + 3] = f2bf(v.w);
    }
    __syncthreads();
    int j = t >> 2, cg = (t & 3) * 16;               // j = local n, cg = 16-wide c chunk
    alignas(16) unsigned short tmp[16];
#pragma unroll
    for (int i = 0; i < 16; i++) tmp[i] = tile[cg + i][j];
    unsigned short* dst = xT + ((size_t)b * NN + n0 + j) * NC + c0 + cg;
    *(uint4*)(dst) = *(const uint4*)(tmp);
    *(uint4*)(dst + 8) = *(const uint4*)(tmp + 8);
}

// K3: partial xbar[sl][b][h][c] = sum_{n in slice} sT[b][n][h] * xT[b][n][c]
__global__ void xbar_kernel(const unsigned short* __restrict__ xT, const float* __restrict__ sT,
                            float* __restrict__ xbarP) {
    int b = blockIdx.z, sl = blockIdx.y, ch = blockIdx.x;   // ch in {0,1}
    int t = threadIdx.x;                                    // 256
    int c = ch * 256 + t;
    float acc[8] = {};
    const unsigned short* xp = xT + ((size_t)b * NN + sl * 256) * NC + c;
    const float* sp = sT + ((size_t)b * NN + sl * 256) * 8;  // uniform -> SGPR loads
    for (int n = 0; n < 256; n++) {
        float xv = bf2f(xp[(size_t)n * NC]);
#pragma unroll
        for (int h = 0; h < 8; h++) acc[h] += sp[n * 8 + h] * xv;
    }
#pragma unroll
    for (int h = 0; h < 8; h++)
        xbarP[(((size_t)sl * NB + b) * 8 + h) * NC + c] = acc[h];
}

// K4: ctx[b][h*64+d] = Wk[h,d,:].xbar[b,h,:] + bk[h,d]
__global__ void ctx_kernel(const float* __restrict__ xbarP, const float* __restrict__ Wqkv,
                           const float* __restrict__ bqkv, float* __restrict__ ctx) {
    int bh = blockIdx.x; int b = bh >> 3, h = bh & 7;
    int t = threadIdx.x;                                    // 256
    __shared__ float xb[512];
    for (int i = t; i < 512; i += 256) {
        float s = 0.f;
        for (int sl = 0; sl < 16; sl++) s += xbarP[(((size_t)sl * NB + b) * 8 + h) * NC + i];
        xb[i] = s;
    }
    __syncthreads();
    int d = t >> 2, sub = t & 3;
    const float* wk = Wqkv + ((size_t)h * 129 + 1 + d) * 512;
    float acc = 0.f;
    for (int i = sub * 4; i < 512; i += 16) {
        float4 w = *(const float4*)(wk + i);
        acc += w.x * xb[i] + w.y * xb[i + 1] + w.z * xb[i + 2] + w.w * xb[i + 3];
    }
    acc += __shfl_xor(acc, 1);
    acc += __shfl_xor(acc, 2);
    if (sub == 0) ctx[(size_t)b * NC + h * 64 + d] = acc + bqkv[h * 129 + 1 + d];
}

// K5/K6: C[512 x 4096] = A[512x512] * B^T  (B stored as [n][k] bf16 rows), per batch.
// MODE 0: epilogue relu(acc+bv)*ctx -> bf16, written TRANSPOSED mT[b][n][j].
// MODE 1: epilogue acc+bp -> fp32 out[b][o][n].
template <int MODE>
__global__ __launch_bounds__(512) void gemm_kernel(
    const unsigned short* __restrict__ A,     // [512][512] bf16 row-major
    const unsigned short* __restrict__ Bmat,  // [B][4096][512] bf16
    const float* __restrict__ bias,           // bv or bp
    const float* __restrict__ ctx,            // [B][512] (MODE 0)
    unsigned short* __restrict__ mT,          // MODE 0 output
    float* __restrict__ outp)                 // MODE 1 output
{
    __shared__ alignas(16) unsigned short As[256 * 32];   // [m][k]
    __shared__ alignas(16) unsigned short Bs[128 * 32];   // [n][k]
    int b = blockIdx.z;
    int m0 = blockIdx.y * 256, n0 = blockIdx.x * 128;
    int t = threadIdx.x;
    int lane = t & 63;
    int wid = t >> 6;
    int wm = wid >> 1, wn = wid & 1;                      // 4x2 wave grid, 64x64 per wave

    const unsigned short* Bb = Bmat + ((size_t)b * NN + n0) * NC;

    f32x4 acc[4][4];
#pragma unroll
    for (int i = 0; i < 4; i++)
#pragma unroll
        for (int j = 0; j < 4; j++) { f32x4 z = {0.f, 0.f, 0.f, 0.f}; acc[i][j] = z; }

    for (int kk = 0; kk < 512; kk += 32) {
        // stage A (256x32) : units t and t+512 ; stage B (128x32): unit t
        {
            int u = t, row = u >> 2, kg = u & 3;
            uint4 va = *(const uint4*)(A + (size_t)(m0 + row) * 512 + kk + kg * 8);
            *(uint4*)(As + (size_t)u * 8) = va;
            u = t + 512; row = u >> 2; kg = u & 3;
            uint4 vb = *(const uint4*)(A + (size_t)(m0 + row) * 512 + kk + kg * 8);
            *(uint4*)(As + (size_t)u * 8) = vb;
            u = t; row = u >> 2; kg = u & 3;
            uint4 vc = *(const uint4*)(Bb + (size_t)row * 512 + kk + kg * 8);
            *(uint4*)(Bs + (size_t)u * 8) = vc;
        }
        __syncthreads();
        bf16x8 af[4], bfr[4];
        int koff = (lane >> 4) * 8;
        int arow = wm * 64 + (lane & 15);
        int brow = wn * 64 + (lane & 15);
#pragma unroll
        for (int i = 0; i < 4; i++) af[i]  = *(const bf16x8*)(As + (size_t)(arow + i * 16) * 32 + koff);
#pragma unroll
        for (int j = 0; j < 4; j++) bfr[j] = *(const bf16x8*)(Bs + (size_t)(brow + j * 16) * 32 + koff);
#pragma unroll
        for (int i = 0; i < 4; i++)
#pragma unroll
            for (int j = 0; j < 4; j++)
                acc[i][j] = __builtin_amdgcn_mfma_f32_16x16x32_bf16(af[i], bfr[j], acc[i][j], 0, 0, 0);
        __syncthreads();
    }

    // epilogue; D frag: col = lane&15, row = (lane>>4)*4 + reg
    int g = lane >> 4, col = lane & 15;
#pragma unroll
    for (int i = 0; i < 4; i++) {
        int j0 = m0 + wm * 64 + i * 16 + g * 4;           // 4 consecutive output rows
        if (MODE == 0) {
            float4 bv4 = *(const float4*)(bias + j0);
            float4 cx4 = *(const float4*)(ctx + (size_t)b * NC + j0);
#pragma unroll
            for (int j = 0; j < 4; j++) {
                int n = n0 + wn * 64 + j * 16 + col;
                f32x4 a = acc[i][j];
                unsigned short h0 = f2bf(fmaxf(a[0] + bv4.x, 0.f) * cx4.x);
                unsigned short h1 = f2bf(fmaxf(a[1] + bv4.y, 0.f) * cx4.y);
                unsigned short h2 = f2bf(fmaxf(a[2] + bv4.z, 0.f) * cx4.z);
                unsigned short h3 = f2bf(fmaxf(a[3] + bv4.w, 0.f) * cx4.w);
                uint2 pk;
                pk.x = (unsigned)h0 | ((unsigned)h1 << 16);
                pk.y = (unsigned)h2 | ((unsigned)h3 << 16);
                *(uint2*)(mT + ((size_t)b * NN + n) * NC + j0) = pk;
            }
        } else {
            float4 bp4 = *(const float4*)(bias + j0);
#pragma unroll
            for (int j = 0; j < 4; j++) {
                int n = n0 + wn * 64 + j * 16 + col;
                f32x4 a = acc[i][j];
                float* op = outp + (size_t)b * NC * NN + (size_t)j0 * NN + n;
                op[0]          = a[0] + bp4.x;
                op[NN]         = a[1] + bp4.y;
                op[2 * (size_t)NN] = a[2] + bp4.z;
                op[3 * (size_t)NN] = a[3] + bp4.w;
            }
        }
    }
}

extern "C" void kernel_launch(void* const* d_in, const int* in_sizes, int n_in,
                              void* d_out, int out_size, void* d_ws, size_t ws_size,
                              hipStream_t stream) {
    const float* x    = (const float*)d_in[0];
    const float* Wqkv = (const float*)d_in[1];
    const float* bqkv = (const float*)d_in[2];
    const float* Wp   = (const float*)d_in[3];
    const float* bp   = (const float*)d_in[4];
    float* outp = (float*)d_out;

    // ws layout. mT occupies [0, 64MB+); q/sT/xbarP live in mT's range but are
    // fully consumed (K1..K4) before K5 writes mT. ctx/Wv/Wp/bv are separate.
    char* ws = (char*)d_ws;
    unsigned short* mT = (unsigned short*)ws;                        // 67108864 B
    float* q     = (float*)(ws);                                     // 2 MB (dead before K5)
    float* sT    = (float*)(ws + 2097152);                           // 2 MB (dead before K5)
    float* xbarP = (float*)(ws + 4194304);                           // 4 MB (dead before K5)
    float* ctx   = (float*)(ws + 67108864);                          // 32 KB
    unsigned short* Wv_bf = (unsigned short*)(ws + 67108864 + 32768);            // 512 KB
    unsigned short* Wp_bf = (unsigned short*)(ws + 67108864 + 32768 + 524288);   // 512 KB
    float* bv    = (float*)(ws + 67108864 + 32768 + 1048576);        // 2 KB
    // xT (bf16 transposed x, 67MB) lives in d_out's first half; K6 overwrites all of d_out.
    unsigned short* xT = (unsigned short*)d_out;

    pack_kernel<<<dim3(1024), 256, 0, stream>>>(Wqkv, bqkv, Wp, Wv_bf, Wp_bf, bv);
    q_kernel<<<dim3(16, 16), 256, 0, stream>>>(x, Wqkv, bqkv, q);
    softmax_kernel<<<dim3(128), 256, 0, stream>>>(q, sT);
    transpose_kernel<<<dim3(64, 8, 16), 256, 0, stream>>>(x, xT);
    xbar_kernel<<<dim3(2, 16, 16), 256, 0, stream>>>(xT, sT, xbarP);
    ctx_kernel<<<dim3(128), 256, 0, stream>>>(xbarP, Wqkv, bqkv, ctx);
    gemm_kernel<0><<<dim3(32, 2, 16), 512, 0, stream>>>(Wv_bf, xT, bv, ctx, mT, nullptr);
    gemm_kernel<1><<<dim3(32, 2, 16), 512, 0, stream>>>(Wp_bf, mT, bp, nullptr, nullptr, outp);
}

// Round 2
// 209.146 us; speedup vs baseline: 1.3172x; 1.3172x over previous
//
#include <hip/hip_runtime.h>

// Problem constants: B=16, DIM(C)=512, N=4096, H=8, HD=64, QKV rows = 8*129 = 1032.
#define NB 16
#define NC 512
#define NN 4096
#define NH 8

typedef __attribute__((ext_vector_type(8))) __bf16 bf16x8;
typedef __attribute__((ext_vector_type(4))) float f32x4;

__device__ __forceinline__ unsigned short f2bf(float f) {
    union { float f; unsigned u; } x; x.f = f;
    unsigned r = x.u + 0x7FFF + ((x.u >> 16) & 1);   // round-to-nearest-even
    return (unsigned short)(r >> 16);
}
__device__ __forceinline__ float bits2f(unsigned u) {
    union { unsigned u; float f; } x; x.u = u; return x.f;
}

// K0: repack Wv rows (head-interleaved) + Wp to bf16, gather bv.
__global__ void pack_kernel(const float* __restrict__ Wqkv, const float* __restrict__ bqkv,
                            const float* __restrict__ Wp,
                            unsigned short* __restrict__ Wv_bf, unsigned short* __restrict__ Wp_bf,
                            float* __restrict__ bv) {
    int t = blockIdx.x * 256 + threadIdx.x;          // 0 .. 512*512-1
    int j = t >> 9, c = t & 511;
    int h = j >> 6, d = j & 63;
    Wv_bf[t] = f2bf(Wqkv[((size_t)h * 129 + 65 + d) * 512 + c]);
    Wp_bf[t] = f2bf(Wp[t]);
    if (t < 512) bv[t] = bqkv[(t >> 6) * 129 + 65 + (t & 63)];
}

// K1: fused transpose + q-partial.
//   x [b][c][n] fp32  ->  xT [b][n][c] bf16
//   qP[cblk][b][h][n] = sum_{c in cblk} Wq[h,c] * x[b,c,n]   (fp32 exact)
__global__ void transpose_q_kernel(const float* __restrict__ x, const float* __restrict__ Wqkv,
                                   unsigned short* __restrict__ xT, float* __restrict__ qP) {
    __shared__ unsigned short tile[64][66];          // pad breaks bank conflicts
    __shared__ float Ws[8][64];
    __shared__ float qw[4][8][64];                   // per-wave q partials
    int b = blockIdx.z, c0 = blockIdx.y * 64, n0 = blockIdx.x * 64;
    int t = threadIdx.x;                             // 256
    for (int i = t; i < 512; i += 256)
        Ws[i >> 6][i & 63] = Wqkv[(size_t)(i >> 6) * (129 * 512) + c0 + (i & 63)];
    __syncthreads();
    int r = t >> 4, cc = (t & 15) * 4;
    const float* xp = x + ((size_t)b * NC + c0) * NN + n0;
    float accq[8][4];
#pragma unroll
    for (int h = 0; h < 8; h++)
#pragma unroll
        for (int j = 0; j < 4; j++) accq[h][j] = 0.f;
#pragma unroll
    for (int p = 0; p < 4; p++) {
        int row = r + p * 16;
        float4 v = *(const float4*)(xp + (size_t)row * NN + cc);
        tile[row][cc + 0] = f2bf(v.x);
        tile[row][cc + 1] = f2bf(v.y);
        tile[row][cc + 2] = f2bf(v.z);
        tile[row][cc + 3] = f2bf(v.w);
#pragma unroll
        for (int h = 0; h < 8; h++) {
            float w = Ws[h][row];
            accq[h][0] += w * v.x;
            accq[h][1] += w * v.y;
            accq[h][2] += w * v.z;
            accq[h][3] += w * v.w;
        }
    }
    __syncthreads();
    // transposed bf16 write
    {
        int j = t >> 2, cg = (t & 3) * 16;           // j = local n, cg = 16-wide c chunk
        alignas(16) unsigned short tmp[16];
#pragma unroll
        for (int i = 0; i < 16; i++) tmp[i] = tile[cg + i][j];
        unsigned short* dst = xT + ((size_t)b * NN + n0 + j) * NC + c0 + cg;
        *(uint4*)(dst) = *(const uint4*)(tmp);
        *(uint4*)(dst + 8) = *(const uint4*)(tmp + 8);
    }
    // q reduce: sum over the wave's 4 r-groups (lane bits 4,5), then across waves via LDS
    int lane = t & 63, w = t >> 6;
#pragma unroll
    for (int h = 0; h < 8; h++)
#pragma unroll
        for (int j = 0; j < 4; j++) {
            float a = accq[h][j];
            a += __shfl_xor(a, 16);
            a += __shfl_xor(a, 32);
            accq[h][j] = a;
        }
    if (lane < 16) {
#pragma unroll
        for (int h = 0; h < 8; h++)
#pragma unroll
            for (int j = 0; j < 4; j++) qw[w][h][lane * 4 + j] = accq[h][j];
    }
    __syncthreads();
    for (int i = t; i < 512; i += 256) {
        int h = i >> 6, n = i & 63;
        float s = qw[0][h][n] + qw[1][h][n] + qw[2][h][n] + qw[3][h][n];
        qP[(((size_t)blockIdx.y * NB + b) * 8 + h) * NN + n0 + n] = s;
    }
}

// K2: softmax over N per (b,h) of q = sum of 8 c-block partials (bias dropped: shift-invariant).
// Writes TRANSPOSED scores sT[b][n][h] (fp32).
__global__ void softmax_kernel(const float* __restrict__ qP, float* __restrict__ sT) {
    int bh = blockIdx.x;                 // b*8+h
    int b = bh >> 3, h = bh & 7;
    int t = threadIdx.x;                 // 256
    __shared__ float red[8];
    const float* qp = qP + (size_t)bh * NN;
    const size_t cstr = (size_t)NB * 8 * NN;         // c-block stride in qP
    float v[16];
    float mx = -1e30f;
#pragma unroll
    for (int i = 0; i < 16; i++) {
        int n = t + i * 256;
        float s = 0.f;
#pragma unroll
        for (int cb = 0; cb < 8; cb++) s += qp[cb * cstr + n];
        v[i] = s; mx = fmaxf(mx, s);
    }
#pragma unroll
    for (int o = 32; o; o >>= 1) mx = fmaxf(mx, __shfl_xor(mx, o));
    if ((t & 63) == 0) red[t >> 6] = mx;
    __syncthreads();
    mx = fmaxf(fmaxf(red[0], red[1]), fmaxf(red[2], red[3]));
    float s = 0.f;
#pragma unroll
    for (int i = 0; i < 16; i++) { v[i] = __expf(v[i] - mx); s += v[i]; }
#pragma unroll
    for (int o = 32; o; o >>= 1) s += __shfl_xor(s, o);
    __syncthreads();
    if ((t & 63) == 0) red[4 + (t >> 6)] = s;
    __syncthreads();
    float inv = 1.f / (red[4] + red[5] + red[6] + red[7]);
#pragma unroll
    for (int i = 0; i < 16; i++) {
        int n = t + i * 256;
        sT[((size_t)b * NN + n) * 8 + h] = v[i] * inv;
    }
}

// K3: partial xbar[sl64][b][h][c] = sum_{n in 64-slice} sT[b][n][h] * xT[b][n][c]
// Each lane owns 8 consecutive c (one 16B load/row); each wave one 64-n slice.
__global__ void xbar_kernel(const unsigned short* __restrict__ xT, const float* __restrict__ sT,
                            float* __restrict__ xbarP) {
    int b = blockIdx.y, sl = blockIdx.x;                 // 16 slices of 256 n
    int t = threadIdx.x;
    int g = __builtin_amdgcn_readfirstlane(t >> 6);      // wave id (uniform)
    int lane = t & 63;
    int c8 = lane * 8;
    int nbase = sl * 256 + g * 64;
    float acc[8][8];
#pragma unroll
    for (int h = 0; h < 8; h++)
#pragma unroll
        for (int c = 0; c < 8; c++) acc[h][c] = 0.f;
    const unsigned short* xp = xT + ((size_t)b * NN + nbase) * NC + c8;
    const float* sp = sT + ((size_t)b * NN + nbase) * 8;
    for (int i = 0; i < 64; i++) {
        uint4 xv = *(const uint4*)(xp + (size_t)i * NC);
        float xf[8];
        xf[0] = bits2f(xv.x << 16); xf[1] = bits2f(xv.x & 0xFFFF0000u);
        xf[2] = bits2f(xv.y << 16); xf[3] = bits2f(xv.y & 0xFFFF0000u);
        xf[4] = bits2f(xv.z << 16); xf[5] = bits2f(xv.z & 0xFFFF0000u);
        xf[6] = bits2f(xv.w << 16); xf[7] = bits2f(xv.w & 0xFFFF0000u);
#pragma unroll
        for (int h = 0; h < 8; h++) {
            float s = sp[i * 8 + h];
#pragma unroll
            for (int c = 0; c < 8; c++) acc[h][c] += s * xf[c];
        }
    }
#pragma unroll
    for (int h = 0; h < 8; h++) {
        float* dst = xbarP + (((size_t)(sl * 4 + g) * NB + b) * 8 + h) * NC + c8;
        f32x4 lo = {acc[h][0], acc[h][1], acc[h][2], acc[h][3]};
        f32x4 hi = {acc[h][4], acc[h][5], acc[h][6], acc[h][7]};
        *(f32x4*)(dst) = lo;
        *(f32x4*)(dst + 4) = hi;
    }
}

// K4: ctx[b][h*64+d] = Wk[h,d,:].xbar[b,h,:] + bk[h,d]   (sums 64 partial slices)
__global__ void ctx_kernel(const float* __restrict__ xbarP, const float* __restrict__ Wqkv,
                           const float* __restrict__ bqkv, float* __restrict__ ctx) {
    int bh = blockIdx.x; int b = bh >> 3, h = bh & 7;
    int t = threadIdx.x;                                    // 256
    __shared__ float xb[512];
    for (int i = t; i < 512; i += 256) {
        float s = 0.f;
        for (int sl = 0; sl < 64; sl++) s += xbarP[(((size_t)sl * NB + b) * 8 + h) * NC + i];
        xb[i] = s;
    }
    __syncthreads();
    int d = t >> 2, sub = t & 3;
    const float* wk = Wqkv + ((size_t)h * 129 + 1 + d) * 512;
    float acc = 0.f;
    for (int i = sub * 4; i < 512; i += 16) {
        float4 w = *(const float4*)(wk + i);
        acc += w.x * xb[i] + w.y * xb[i + 1] + w.z * xb[i + 2] + w.w * xb[i + 3];
    }
    acc += __shfl_xor(acc, 1);
    acc += __shfl_xor(acc, 2);
    if (sub == 0) ctx[(size_t)b * NC + h * 64 + d] = acc + bqkv[h * 129 + 1 + d];
}

// K5/K6: C[512 x 4096] = A[512x512] * B^T  (B stored as [n][k] bf16 rows), per batch.
// MODE 0: epilogue relu(acc+bv)*ctx -> bf16, written TRANSPOSED mT[b][n][j].
// MODE 1: epilogue acc+bp -> fp32 out[b][o][n].
template <int MODE>
__global__ __launch_bounds__(512) void gemm_kernel(
    const unsigned short* __restrict__ A,     // [512][512] bf16 row-major
    const unsigned short* __restrict__ Bmat,  // [B][4096][512] bf16
    const float* __restrict__ bias,           // bv or bp
    const float* __restrict__ ctx,            // [B][512] (MODE 0)
    unsigned short* __restrict__ mT,          // MODE 0 output
    float* __restrict__ outp)                 // MODE 1 output
{
    __shared__ alignas(16) unsigned short As[256 * 32];   // [m][k]
    __shared__ alignas(16) unsigned short Bs[128 * 32];   // [n][k]
    int b = blockIdx.z;
    int m0 = blockIdx.y * 256, n0 = blockIdx.x * 128;
    int t = threadIdx.x;
    int lane = t & 63;
    int wid = t >> 6;
    int wm = wid >> 1, wn = wid & 1;                      // 4x2 wave grid, 64x64 per wave

    const unsigned short* Bb = Bmat + ((size_t)b * NN + n0) * NC;

    f32x4 acc[4][4];
#pragma unroll
    for (int i = 0; i < 4; i++)
#pragma unroll
        for (int j = 0; j < 4; j++) { f32x4 z = {0.f, 0.f, 0.f, 0.f}; acc[i][j] = z; }

    for (int kk = 0; kk < 512; kk += 32) {
        {
            int u = t, row = u >> 2, kg = u & 3;
            uint4 va = *(const uint4*)(A + (size_t)(m0 + row) * 512 + kk + kg * 8);
            *(uint4*)(As + (size_t)u * 8) = va;
            u = t + 512; row = u >> 2; kg = u & 3;
            uint4 vb = *(const uint4*)(A + (size_t)(m0 + row) * 512 + kk + kg * 8);
            *(uint4*)(As + (size_t)u * 8) = vb;
            u = t; row = u >> 2; kg = u & 3;
            uint4 vc = *(const uint4*)(Bb + (size_t)row * 512 + kk + kg * 8);
            *(uint4*)(Bs + (size_t)u * 8) = vc;
        }
        __syncthreads();
        bf16x8 af[4], bfr[4];
        int koff = (lane >> 4) * 8;
        int arow = wm * 64 + (lane & 15);
        int brow = wn * 64 + (lane & 15);
#pragma unroll
        for (int i = 0; i < 4; i++) af[i]  = *(const bf16x8*)(As + (size_t)(arow + i * 16) * 32 + koff);
#pragma unroll
        for (int j = 0; j < 4; j++) bfr[j] = *(const bf16x8*)(Bs + (size_t)(brow + j * 16) * 32 + koff);
#pragma unroll
        for (int i = 0; i < 4; i++)
#pragma unroll
            for (int j = 0; j < 4; j++)
                acc[i][j] = __builtin_amdgcn_mfma_f32_16x16x32_bf16(af[i], bfr[j], acc[i][j], 0, 0, 0);
        __syncthreads();
    }

    // epilogue; D frag: col = lane&15, row = (lane>>4)*4 + reg
    int g = lane >> 4, col = lane & 15;
#pragma unroll
    for (int i = 0; i < 4; i++) {
        int j0 = m0 + wm * 64 + i * 16 + g * 4;           // 4 consecutive output rows
        if (MODE == 0) {
            float4 bv4 = *(const float4*)(bias + j0);
            float4 cx4 = *(const float4*)(ctx + (size_t)b * NC + j0);
#pragma unroll
            for (int j = 0; j < 4; j++) {
                int n = n0 + wn * 64 + j * 16 + col;
                f32x4 a = acc[i][j];
                unsigned short h0 = f2bf(fmaxf(a[0] + bv4.x, 0.f) * cx4.x);
                unsigned short h1 = f2bf(fmaxf(a[1] + bv4.y, 0.f) * cx4.y);
                unsigned short h2 = f2bf(fmaxf(a[2] + bv4.z, 0.f) * cx4.z);
                unsigned short h3 = f2bf(fmaxf(a[3] + bv4.w, 0.f) * cx4.w);
                uint2 pk;
                pk.x = (unsigned)h0 | ((unsigned)h1 << 16);
                pk.y = (unsigned)h2 | ((unsigned)h3 << 16);
                *(uint2*)(mT + ((size_t)b * NN + n) * NC + j0) = pk;
            }
        } else {
            float4 bp4 = *(const float4*)(bias + j0);
#pragma unroll
            for (int j = 0; j < 4; j++) {
                int n = n0 + wn * 64 + j * 16 + col;
                f32x4 a = acc[i][j];
                float* op = outp + (size_t)b * NC * NN + (size_t)j0 * NN + n;
                op[0]              = a[0] + bp4.x;
                op[NN]             = a[1] + bp4.y;
                op[2 * (size_t)NN] = a[2] + bp4.z;
                op[3 * (size_t)NN] = a[3] + bp4.w;
            }
        }
    }
}

extern "C" void kernel_launch(void* const* d_in, const int* in_sizes, int n_in,
                              void* d_out, int out_size, void* d_ws, size_t ws_size,
                              hipStream_t stream) {
    const float* x    = (const float*)d_in[0];
    const float* Wqkv = (const float*)d_in[1];
    const float* bqkv = (const float*)d_in[2];
    const float* Wp   = (const float*)d_in[3];
    const float* bp   = (const float*)d_in[4];
    float* outp = (float*)d_out;

    // ws layout. mT occupies [0, 64MB). sT/qP/xbarP overlap mT's range but are
    // fully consumed (K1..K4) before K5 writes mT. ctx/Wv/Wp/bv live past 64MB.
    char* ws = (char*)d_ws;
    unsigned short* mT = (unsigned short*)ws;                         // 64 MB
    float* sT    = (float*)(ws + 2097152);                            // [2MB,4MB)
    float* qP    = (float*)(ws + 4194304);                            // [4MB,20MB)
    float* xbarP = (float*)(ws + 20971520);                           // [20MB,36MB)
    float* ctx   = (float*)(ws + 67108864);                           // 32 KB
    unsigned short* Wv_bf = (unsigned short*)(ws + 67108864 + 32768);            // 512 KB
    unsigned short* Wp_bf = (unsigned short*)(ws + 67108864 + 32768 + 524288);   // 512 KB
    float* bv    = (float*)(ws + 67108864 + 32768 + 1048576);         // 2 KB
    // xT (bf16 transposed x, 64MB) lives in d_out's first half; K6 overwrites all of d_out.
    unsigned short* xT = (unsigned short*)d_out;

    pack_kernel<<<dim3(1024), 256, 0, stream>>>(Wqkv, bqkv, Wp, Wv_bf, Wp_bf, bv);
    transpose_q_kernel<<<dim3(64, 8, 16), 256, 0, stream>>>(x, Wqkv, xT, qP);
    softmax_kernel<<<dim3(128), 256, 0, stream>>>(qP, sT);
    xbar_kernel<<<dim3(16, 16), 256, 0, stream>>>(xT, sT, xbarP);
    ctx_kernel<<<dim3(128), 256, 0, stream>>>(xbarP, Wqkv, bqkv, ctx);
    gemm_kernel<0><<<dim3(32, 2, 16), 512, 0, stream>>>(Wv_bf, xT, bv, ctx, mT, nullptr);
    gemm_kernel<1><<<dim3(32, 2, 16), 512, 0, stream>>>(Wp_bf, mT, bp, nullptr, nullptr, outp);
}